// Round 4
// baseline (929.740 us; speedup 1.0000x reference)
//
#include <hip/hip_runtime.h>

typedef float f32x4 __attribute__((ext_vector_type(4)));
typedef _Float16 f16x8 __attribute__((ext_vector_type(8)));

// ---- LDS layout (both kernels, 64528 B, static) ----
// All regions use ADDITIVE swizzles: per-lane base + compile-time offsets,
// bank-even (8 lanes / 16B-slot, distinct rows) by construction.
#define OFF_W2H 0       /* f16 hi W2: 128 rows, stride 288; byte kb*64+16*gp */
#define OFF_WL8 36864   /* fp8 lo W2 (x4096): 128 rows, stride 136; kb*32+8*gp */
#define OFF_W1  54272   /* K-packed 3-term W1: 128 rows, stride 64; 16*gp     */
#define OFF_W3  62464   /* f16 hi W3, rows replicated: 4 rows, stride 256     */
#define OFF_B1  63488
#define OFF_B2  64000
#define OFF_B3  64512
#define LDS_BYTES 64528

__device__ inline float kdet(float a, float b, float c, float d) {
    float w = b * c;
    float e = fmaf(b, c, -w);
    return fmaf(a, d, -w) - e;   // Kahan det: sign matches f64 ref branch
}

__device__ inline void polar2(float a, float b, float c, float d, float det,
                              float& R00, float& R01, float& R10, float& R11) {
    if (det >= 0.f) {
        float h1 = a + d, h2 = c - b;
        float q = fmaxf(sqrtf(h1 * h1 + h2 * h2), 1e-30f);
        float iq = 1.f / q;
        R00 = h1 * iq; R01 = -h2 * iq; R10 = h2 * iq; R11 = h1 * iq;
    } else {
        float h1 = a - d, h2 = b + c;
        float q = fmaxf(sqrtf(h1 * h1 + h2 * h2), 1e-30f);
        float iq = 1.f / q;
        R00 = h1 * iq; R01 = h2 * iq; R10 = h2 * iq; R11 = -h1 * iq;
    }
}

// Logical K-slot map (A and B sides identical -> permutation cancels):
// k(g,e) = 4g + (e&3) + 16*(e>>2).  Hidden-channel map (C/D absorb):
// c(g,e,kb) = 32kb + 16*(e>>2) + 4g + (e&3).  Physical g-slot: gp = g^(row&3).
__device__ inline void stage_weights(unsigned char* s, const float* w1, int D,
                                     const float* b1, const float* w2, const float* b2,
                                     const float* w3, const float* b3) {
    const int tid = threadIdx.x, nt = blockDim.x;
    for (int idx = tid; idx < 2048; idx += nt) {           // W2 hi(f16)+lo(fp8)
        int j = idx >> 4, kb = (idx >> 2) & 3, gp = idx & 3;
        int gL = gp ^ (j & 3);
        f16x8 vh;
        float lo[8];
        #pragma unroll
        for (int e = 0; e < 8; ++e) {
            int k = kb * 32 + 4 * gL + (e & 3) + 16 * (e >> 2);
            float w = w2[j * 128 + k];
            _Float16 h = (_Float16)w;
            vh[e] = h;
            lo[e] = (w - (float)h) * 4096.0f;              // 2^12 pre-scale
        }
        *(f16x8*)(s + OFF_W2H + j * 288 + kb * 64 + 16 * gp) = vh;
        int p0 = __builtin_amdgcn_cvt_pk_fp8_f32(lo[0], lo[1], 0, false);
        p0 = __builtin_amdgcn_cvt_pk_fp8_f32(lo[2], lo[3], p0, true);
        int p1 = __builtin_amdgcn_cvt_pk_fp8_f32(lo[4], lo[5], 0, false);
        p1 = __builtin_amdgcn_cvt_pk_fp8_f32(lo[6], lo[7], p1, true);
        *(int*)(s + OFF_WL8 + j * 136 + kb * 32 + 8 * gp) = p0;
        *(int*)(s + OFF_WL8 + j * 136 + kb * 32 + 8 * gp + 4) = p1;
    }
    // W1 K-packed 3-term: k<D: Wh (pairs xh); [8,8+D): Wh (pairs xl);
    // [16,16+D): Wl (pairs xh); else 0.
    for (int idx = tid; idx < 512; idx += nt) {            // (j,gp)
        int j = idx >> 2, gp = idx & 3;
        int gL = gp ^ (j & 3);
        f16x8 v;
        #pragma unroll
        for (int e = 0; e < 8; ++e) {
            int k = 4 * gL + (e & 3) + 16 * (e >> 2);
            _Float16 val = (_Float16)0.f;
            if (k < D) val = (_Float16)w1[j * D + k];
            else if (k >= 8 && k < 8 + D) val = (_Float16)w1[j * D + (k - 8)];
            else if (k >= 16 && k < 16 + D) {
                float w = w1[j * D + (k - 16)];
                val = (_Float16)(w - (float)(_Float16)w);
            }
            v[e] = val;
        }
        *(f16x8*)(s + OFF_W1 + j * 64 + 16 * gp) = v;
    }
    for (int idx = tid; idx < 64; idx += nt) {             // W3 hi, rows 0..3
        int r = idx >> 4, kb = (idx >> 2) & 3, gp = idx & 3;
        int gL = gp ^ r;
        f16x8 v;
        #pragma unroll
        for (int e = 0; e < 8; ++e) {
            int c = 32 * kb + 16 * (e >> 2) + 4 * gL + (e & 3);
            v[e] = (_Float16)w3[r * 128 + c];
        }
        *(f16x8*)(s + OFF_W3 + r * 256 + kb * 64 + 16 * gp) = v;
    }
    for (int idx = tid; idx < 128; idx += nt) {
        ((float*)(s + OFF_B1))[idx] = b1[idx];
        ((float*)(s + OFF_B2))[idx] = b2[idx];
    }
    if (tid < 4) ((float*)(s + OFF_B3))[tid] = b3[tid];
}

// Branchless layer-1 B fragment.  g0:{h0..3,h0..3} g1:{h4..7,h4..7}
// g2:{l0..3,0} g3:{l4..7,0}  (2nd half of g<2 pairs the Wl slots).
__device__ inline f16x8 build_b1(const float in[8], int g) {
    const bool half2 = (g & 1);
    float t0 = half2 ? in[4] : in[0];
    float t1 = half2 ? in[5] : in[1];
    float t2 = half2 ? in[6] : in[2];
    float t3 = half2 ? in[7] : in[3];
    _Float16 h0 = (_Float16)t0, h1 = (_Float16)t1;
    _Float16 h2 = (_Float16)t2, h3 = (_Float16)t3;
    _Float16 l0 = (_Float16)(t0 - (float)h0), l1 = (_Float16)(t1 - (float)h1);
    _Float16 l2 = (_Float16)(t2 - (float)h2), l3 = (_Float16)(t3 - (float)h3);
    const bool hi = (g < 2);
    const _Float16 z = (_Float16)0.f;
    f16x8 b;
    b[0] = hi ? h0 : l0; b[1] = hi ? h1 : l1;
    b[2] = hi ? h2 : l2; b[3] = hi ? h3 : l3;
    b[4] = hi ? h0 : z;  b[5] = hi ? h1 : z;
    b[6] = hi ? h2 : z;  b[7] = hi ? h3 : z;
    return b;
}

// MLP: L1 = single K-packed 3-term MFMA/row-block; L2 = f16 hi*(hh,hl) +
// fp8 lo*hi (x 2^-10); L3 = 1-term f16, rows replicated (out on all lanes).
__device__ inline void mlp128(const unsigned char* s, f16x8 b1f, int m, int g,
                              const f32x4 b3q, float xout[4]) {
    const int sw = 16 * (g ^ (m & 3));
    const unsigned char* bW1 = s + OFF_W1 + m * 64 + sw;
    const unsigned char* bHI = s + OFF_W2H + m * 288 + sw;
    const unsigned char* bL8 = s + OFF_WL8 + m * 136 + (sw >> 1);
    const unsigned char* bW3 = s + OFF_W3 + (m & 3) * 256 + sw;
    f32x4 acc[8];
    #pragma unroll
    for (int mb = 0; mb < 8; ++mb) {                       // layer1 (+b1 C-init)
        f32x4 bq = *(const f32x4*)(s + OFF_B1 + mb * 64 + g * 16);
        f16x8 af = *(const f16x8*)(bW1 + mb * 1024);
        acc[mb] = __builtin_amdgcn_mfma_f32_16x16x32_f16(af, b1f, bq, 0, 0, 0);
    }
    f16x8 hh[4], hl[4];
    long x8[4];
    #pragma unroll
    for (int kb = 0; kb < 4; ++kb) {                       // relu + split repack
        float v[8];
        #pragma unroll
        for (int e = 0; e < 8; ++e)
            v[e] = fmaxf(acc[2 * kb + (e >> 2)][e & 3], 0.f);
        #pragma unroll
        for (int e = 0; e < 8; ++e) {
            _Float16 h = (_Float16)v[e];
            hh[kb][e] = h;
            hl[kb][e] = (_Float16)(v[e] - (float)h);
        }
        int p0 = __builtin_amdgcn_cvt_pk_fp8_f32(v[0] * 0.25f, v[1] * 0.25f, 0, false);
        p0 = __builtin_amdgcn_cvt_pk_fp8_f32(v[2] * 0.25f, v[3] * 0.25f, p0, true);
        int p1 = __builtin_amdgcn_cvt_pk_fp8_f32(v[4] * 0.25f, v[5] * 0.25f, 0, false);
        p1 = __builtin_amdgcn_cvt_pk_fp8_f32(v[6] * 0.25f, v[7] * 0.25f, p1, true);
        x8[kb] = (long)(unsigned)p0 | ((long)p1 << 32);
    }
    f32x4 acc2[8];
    #pragma unroll
    for (int mb = 0; mb < 8; ++mb) {                       // layer2
        f32x4 t = *(const f32x4*)(s + OFF_B2 + mb * 64 + g * 16);
        f32x4 a8 = {0.f, 0.f, 0.f, 0.f};
        #pragma unroll
        for (int kb = 0; kb < 4; ++kb) {
            f16x8 ah = *(const f16x8*)(bHI + mb * 4608 + kb * 64);
            long al = *(const long*)(bL8 + mb * 2176 + kb * 32);
            t = __builtin_amdgcn_mfma_f32_16x16x32_f16(ah, hh[kb], t, 0, 0, 0);
            t = __builtin_amdgcn_mfma_f32_16x16x32_f16(ah, hl[kb], t, 0, 0, 0);
            a8 = __builtin_amdgcn_mfma_f32_16x16x32_fp8_fp8(al, x8[kb], a8, 0, 0, 0);
        }
        #pragma unroll
        for (int r = 0; r < 4; ++r)
            acc2[mb][r] = fmaxf(fmaf(a8[r], 9.765625e-4f, t[r]), 0.f);
    }
    f16x8 h2[4];
    #pragma unroll
    for (int kb = 0; kb < 4; ++kb)                         // hi-only repack
        #pragma unroll
        for (int e = 0; e < 8; ++e)
            h2[kb][e] = (_Float16)acc2[2 * kb + (e >> 2)][e & 3];
    f32x4 acc3 = b3q;                                      // layer3 (+b3 C-init)
    #pragma unroll
    for (int kb = 0; kb < 4; ++kb) {
        f16x8 aw = *(const f16x8*)(bW3 + kb * 64);
        acc3 = __builtin_amdgcn_mfma_f32_16x16x32_f16(aw, h2[kb], acc3, 0, 0, 0);
    }
    #pragma unroll
    for (int o = 0; o < 4; ++o) xout[o] = acc3[o];         // valid on ALL lanes
}

__global__ __launch_bounds__(512, 4) void k_dc(const float* __restrict__ Fin,
    const float* __restrict__ w1, const float* __restrict__ b1,
    const float* __restrict__ w2, const float* __restrict__ b2,
    const float* __restrict__ w3, const float* __restrict__ b3,
    float* __restrict__ out, int nelem) {
    __shared__ alignas(16) unsigned char s[LDS_BYTES];
    stage_weights(s, w1, 7, b1, w2, b2, w3, b3);
    __syncthreads();
    const int lane = threadIdx.x & 63;
    const int m = lane & 15, g = lane >> 4;
    const f32x4 b3q = *(const f32x4*)(s + OFF_B3);
    const int wid = blockIdx.x * (blockDim.x >> 6) + (threadIdx.x >> 6);
    const int nw = gridDim.x * (blockDim.x >> 6);
    const int niter = nelem >> 4;
    for (int it = wid; it < niter; it += nw) {
        const int elem = it * 16 + m;
        f32x4 f = ((const f32x4*)Fin)[elem];
        float a = f[0], b = f[1], c = f[2], d = f[3];
        float det = kdet(a, b, c, d);
        float R00, R01, R10, R11;
        polar2(a, b, c, d, det, R00, R01, R10, R11);
        float E = 0.5f * (a + d), Hh = 0.5f * (c - b);
        float Fv = 0.5f * (a - d), G = 0.5f * (b + c);
        float Q = sqrtf(E * E + Hh * Hh), Rr = sqrtf(Fv * Fv + G * G);
        float inv[8];
        inv[0] = Q + Rr - 1.f;
        inv[1] = fabsf(Q - Rr) - 1.f;
        inv[2] = fmaf(a, a, c * c) - 1.f;
        inv[3] = fmaf(a, b, c * d);
        inv[4] = inv[3];
        inv[5] = fmaf(b, b, d * d) - 1.f;
        inv[6] = det - 1.f;
        inv[7] = 0.f;
        f16x8 b1f = build_b1(inv, g);
        float x[4];
        mlp128(s, b1f, m, g, b3q, x);
        float x01 = 0.5f * (x[1] + x[2]);
        float Fp00 = fmaf(R00, x[0], fmaf(R01, x01, a));
        float Fp01 = fmaf(R00, x01, fmaf(R01, x[3], b));
        float Fp10 = fmaf(R10, x[0], fmaf(R11, x01, c));
        float Fp11 = fmaf(R10, x01, fmaf(R11, x[3], d));
        if (g == 0) {
            f32x4 r = {Fp00, Fp01, Fp10, Fp11};
            ((f32x4*)out)[elem] = r;
        }
    }
}

__global__ __launch_bounds__(512, 4) void k_sp(float* io,
    const float* __restrict__ w1, const float* __restrict__ b1,
    const float* __restrict__ w2, const float* __restrict__ b2,
    const float* __restrict__ w3, const float* __restrict__ b3, int nelem) {
    __shared__ alignas(16) unsigned char s[LDS_BYTES];
    stage_weights(s, w1, 3, b1, w2, b2, w3, b3);
    __syncthreads();
    const int lane = threadIdx.x & 63;
    const int m = lane & 15, g = lane >> 4;
    const f32x4 b3q = *(const f32x4*)(s + OFF_B3);
    const int wid = blockIdx.x * (blockDim.x >> 6) + (threadIdx.x >> 6);
    const int nw = gridDim.x * (blockDim.x >> 6);
    const int niter = nelem >> 4;
    for (int it = wid; it < niter; it += nw) {
        const int elem = it * 16 + m;
        f32x4 fp = ((const f32x4*)io)[elem];
        float a = fp[0], b = fp[1], c = fp[2], d = fp[3];
        float det = kdet(a, b, c, d);
        float R00, R01, R10, R11;
        polar2(a, b, c, d, det, R00, R01, R10, R11);
        float E = 0.5f * (a + d), Hh = 0.5f * (c - b);
        float Fv = 0.5f * (a - d), G = 0.5f * (b + c);
        float Q = sqrtf(E * E + Hh * Hh), Rr = sqrtf(Fv * Fv + G * G);
        float inv[8];
        inv[0] = (Q + Rr) + fabsf(Q - Rr) - 2.f;
        inv[1] = fmaf(a, a, fmaf(b, b, fmaf(c, c, d * d))) - 1.f;
        inv[2] = det - 1.f;
        inv[3] = 0.f; inv[4] = 0.f; inv[5] = 0.f; inv[6] = 0.f; inv[7] = 0.f;
        f16x8 b1f = build_b1(inv, g);
        float y[4];
        mlp128(s, b1f, m, g, b3q, y);
        float y01 = 0.5f * (y[1] + y[2]);
        float P00 = fmaf(R00, y[0], R01 * y01);
        float P01 = fmaf(R00, y01, R01 * y[3]);
        float P10 = fmaf(R10, y[0], R11 * y01);
        float P11 = fmaf(R10, y01, R11 * y[3]);
        float C00 = fmaf(P00, a, P01 * b);
        float C01 = fmaf(P00, c, P01 * d);
        float C10 = fmaf(P10, a, P11 * b);
        float C11 = fmaf(P10, c, P11 * d);
        if (g == 0) {
            f32x4 r = {C00, C01, C10, C11};
            ((f32x4*)io)[elem] = r;
        }
    }
}

extern "C" void kernel_launch(void* const* d_in, const int* in_sizes, int n_in,
                              void* d_out, int out_size, void* d_ws, size_t ws_size,
                              hipStream_t stream) {
    const float* F     = (const float*)d_in[0];
    const float* dc_w1 = (const float*)d_in[1];
    const float* dc_b1 = (const float*)d_in[2];
    const float* dc_w2 = (const float*)d_in[3];
    const float* dc_b2 = (const float*)d_in[4];
    const float* dc_w3 = (const float*)d_in[5];
    const float* dc_b3 = (const float*)d_in[6];
    const float* sp_w1 = (const float*)d_in[7];
    const float* sp_b1 = (const float*)d_in[8];
    const float* sp_w2 = (const float*)d_in[9];
    const float* sp_b2 = (const float*)d_in[10];
    const float* sp_w3 = (const float*)d_in[11];
    const float* sp_b3 = (const float*)d_in[12];
    float* out = (float*)d_out;
    const int nelem = in_sizes[0] / 4;
    dim3 grid(512), block(512);                 // 2 blocks/CU, static 64.5KB LDS
    k_dc<<<grid, block, 0, stream>>>(F, dc_w1, dc_b1, dc_w2, dc_b2,
                                     dc_w3, dc_b3, out, nelem);
    k_sp<<<grid, block, 0, stream>>>(out, sp_w1, sp_b1, sp_w2, sp_b2,
                                     sp_w3, sp_b3, nelem);
}

// Round 5
// 525.132 us; speedup vs baseline: 1.7705x; 1.7705x over previous
//
#include <hip/hip_runtime.h>

typedef float f32x4 __attribute__((ext_vector_type(4)));
typedef _Float16 f16x8 __attribute__((ext_vector_type(8)));

// ---- LDS layout (dynamic, 80528 B <= 80KB -> 2 blocks/CU) ----
// Additive swizzle: per-lane base + compile-time offsets. Row strides are
// odd multiples of 16B (272) => 8 lanes/16B-slot (wave64 minimum) for reads.
#define ST2 272
#define OFF_W2H 0       /* f16 hi W2: 128 rows x 272B; byte kb*64 + 16*gp   */
#define OFF_W2L 34816   /* f16 lo W2: 128 rows x 272B                        */
#define OFF_W1  69632   /* K-packed 3-term W1ext (bias col D): 128 x 64B     */
#define OFF_W3H 77824   /* f16 hi W3 replicated: 4 rows x 272B               */
#define OFF_W3L 78912   /* f16 lo W3 replicated: 4 rows x 272B               */
#define OFF_B2  80000   /* f32[128] */
#define OFF_B3  80512   /* f32[4]   */
#define LDS_BYTES 80528

__device__ inline float kdet(float a, float b, float c, float d) {
    float w = b * c;
    float e = fmaf(b, c, -w);
    return fmaf(a, d, -w) - e;   // Kahan det: sign matches f64 ref branch
}

__device__ inline void polar2(float a, float b, float c, float d, float det,
                              float& R00, float& R01, float& R10, float& R11) {
    if (det >= 0.f) {
        float h1 = a + d, h2 = c - b;
        float q = fmaxf(sqrtf(h1 * h1 + h2 * h2), 1e-30f);
        float iq = 1.f / q;
        R00 = h1 * iq; R01 = -h2 * iq; R10 = h2 * iq; R11 = h1 * iq;
    } else {
        float h1 = a - d, h2 = b + c;
        float q = fmaxf(sqrtf(h1 * h1 + h2 * h2), 1e-30f);
        float iq = 1.f / q;
        R00 = h1 * iq; R01 = h2 * iq; R10 = h2 * iq; R11 = -h1 * iq;
    }
}

// Logical K-slot map (A and B sides identical -> permutation cancels):
// k(g,e) = 4g + (e&3) + 16*(e>>2).  Hidden-channel map (C/D absorb):
// c(g,e,kb) = 32kb + 16*(e>>2) + 4g + (e&3).  Physical g-slot: gp = g^(row&3).
// W1ext: D+1 columns, col D = bias (paired with x[D]=1.0; xl[D]=0 exactly).
__device__ inline void stage_weights(unsigned char* s, const float* w1, int D,
                                     const float* b1, const float* w2, const float* b2,
                                     const float* w3, const float* b3) {
    const int tid = threadIdx.x, nt = blockDim.x;
    for (int idx = tid; idx < 2048; idx += nt) {           // W2 hi+lo
        int j = idx >> 4, kb = (idx >> 2) & 3, gp = idx & 3;
        int gL = gp ^ (j & 3);
        f16x8 vh, vl;
        #pragma unroll
        for (int e = 0; e < 8; ++e) {
            int k = kb * 32 + 4 * gL + (e & 3) + 16 * (e >> 2);
            float w = w2[j * 128 + k];
            _Float16 h = (_Float16)w;
            vh[e] = h;
            vl[e] = (_Float16)(w - (float)h);
        }
        int off = j * ST2 + kb * 64 + 16 * gp;
        *(f16x8*)(s + OFF_W2H + off) = vh;
        *(f16x8*)(s + OFF_W2L + off) = vl;
    }
    // W1ext 3-term K-pack: k<8: Wh(col k); [8,16): Wh(col k-8) (pairs xl);
    // [16,24): Wl(col k-16); [24,32): 0.  col(c) = c<D ? w1 : (c==D ? b1 : 0).
    for (int idx = tid; idx < 512; idx += nt) {            // (j,gp)
        int j = idx >> 2, gp = idx & 3;
        int gL = gp ^ (j & 3);
        f16x8 v;
        #pragma unroll
        for (int e = 0; e < 8; ++e) {
            int k = 4 * gL + (e & 3) + 16 * (e >> 2);
            int c = k & 7;
            float w = (c < D) ? w1[j * D + c] : ((c == D) ? b1[j] : 0.f);
            _Float16 val;
            if (k < 16) val = (_Float16)w;                 // hi (xh and xl pair)
            else if (k < 24) val = (_Float16)(w - (float)(_Float16)w);  // lo
            else val = (_Float16)0.f;
            v[e] = val;
        }
        *(f16x8*)(s + OFF_W1 + j * 64 + 16 * gp) = v;
    }
    // W3 replicated rows (A-row i holds channel i&3): 4 phys rows, hi+lo.
    for (int idx = tid; idx < 64; idx += nt) {             // (t,kb,gp)
        int t = idx >> 4, kb = (idx >> 2) & 3, gp = idx & 3;
        int gL = gp ^ t;
        f16x8 vh, vl;
        #pragma unroll
        for (int e = 0; e < 8; ++e) {
            int c = 32 * kb + 16 * (e >> 2) + 4 * gL + (e & 3);
            float w = w3[t * 128 + c];
            _Float16 h = (_Float16)w;
            vh[e] = h;
            vl[e] = (_Float16)(w - (float)h);
        }
        int off = t * ST2 + kb * 64 + 16 * gp;
        *(f16x8*)(s + OFF_W3H + off) = vh;
        *(f16x8*)(s + OFF_W3L + off) = vl;
    }
    for (int idx = tid; idx < 128; idx += nt)
        ((float*)(s + OFF_B2))[idx] = b2[idx];
    if (tid < 4) ((float*)(s + OFF_B3))[tid] = b3[tid];
}

// Layer-1 B fragment.  g0:{h0..3,h0..3} g1:{h4..7,h4..7}
// g2:{l0..3,0} g3:{l4..7,0}.
__device__ inline f16x8 build_b1(const float in[8], int g) {
    const bool half2 = (g & 1);
    float t0 = half2 ? in[4] : in[0];
    float t1 = half2 ? in[5] : in[1];
    float t2 = half2 ? in[6] : in[2];
    float t3 = half2 ? in[7] : in[3];
    _Float16 h0 = (_Float16)t0, h1 = (_Float16)t1;
    _Float16 h2 = (_Float16)t2, h3 = (_Float16)t3;
    _Float16 l0 = (_Float16)(t0 - (float)h0), l1 = (_Float16)(t1 - (float)h1);
    _Float16 l2 = (_Float16)(t2 - (float)h2), l3 = (_Float16)(t3 - (float)h3);
    const bool hi = (g < 2);
    const _Float16 z = (_Float16)0.f;
    f16x8 b;
    b[0] = hi ? h0 : l0; b[1] = hi ? h1 : l1;
    b[2] = hi ? h2 : l2; b[3] = hi ? h3 : l3;
    b[4] = hi ? h0 : z;  b[5] = hi ? h1 : z;
    b[6] = hi ? h2 : z;  b[7] = hi ? h3 : z;
    return b;
}

// Split-f16 3-term MLP (f32 quality): L1 single K-packed MFMA per row-block
// (bias folded); L2/L3 = Wh*xh + Wh*xl + Wl*xh. Outputs on ALL lanes.
__device__ inline void mlp128(const unsigned char* s, f16x8 b1f, int m, int g,
                              const f32x4 b3q, float xout[4]) {
    const f32x4 zero = {0.f, 0.f, 0.f, 0.f};
    const int sw = 16 * (g ^ (m & 3));
    const unsigned char* bW1 = s + OFF_W1 + m * 64 + sw;
    const unsigned char* bH  = s + OFF_W2H + m * ST2 + sw;
    const unsigned char* bL  = s + OFF_W2L + m * ST2 + sw;
    const unsigned char* bWH3 = s + OFF_W3H + (m & 3) * ST2 + sw;
    const unsigned char* bWL3 = s + OFF_W3L + (m & 3) * ST2 + sw;
    const unsigned char* bB2 = s + OFF_B2 + g * 16;
    f32x4 acc[8];
    #pragma unroll
    for (int mb = 0; mb < 8; ++mb) {                       // layer1: 8 MFMAs
        f16x8 af = *(const f16x8*)(bW1 + mb * 1024);
        acc[mb] = __builtin_amdgcn_mfma_f32_16x16x32_f16(af, b1f, zero, 0, 0, 0);
    }
    f16x8 hh[4], hl[4];
    #pragma unroll
    for (int kb = 0; kb < 4; ++kb)                         // relu + split repack
        #pragma unroll
        for (int e = 0; e < 8; ++e) {
            float v = fmaxf(acc[2 * kb + (e >> 2)][e & 3], 0.f);
            _Float16 h = (_Float16)v;
            hh[kb][e] = h;
            hl[kb][e] = (_Float16)(v - (float)h);
        }
    f32x4 acc2[8];
    #pragma unroll
    for (int mb = 0; mb < 8; ++mb) {                       // layer2: 96 MFMAs
        f32x4 t = *(const f32x4*)(bB2 + mb * 64);          // +b2 C-init
        #pragma unroll
        for (int kb = 0; kb < 4; ++kb) {
            f16x8 ah = *(const f16x8*)(bH + mb * 4352 + kb * 64);
            f16x8 al = *(const f16x8*)(bL + mb * 4352 + kb * 64);
            t = __builtin_amdgcn_mfma_f32_16x16x32_f16(ah, hh[kb], t, 0, 0, 0);
            t = __builtin_amdgcn_mfma_f32_16x16x32_f16(ah, hl[kb], t, 0, 0, 0);
            t = __builtin_amdgcn_mfma_f32_16x16x32_f16(al, hh[kb], t, 0, 0, 0);
        }
        acc2[mb] = t;
    }
    f16x8 h2h[4], h2l[4];
    #pragma unroll
    for (int kb = 0; kb < 4; ++kb)                         // relu + split repack
        #pragma unroll
        for (int e = 0; e < 8; ++e) {
            float v = fmaxf(acc2[2 * kb + (e >> 2)][e & 3], 0.f);
            _Float16 h = (_Float16)v;
            h2h[kb][e] = h;
            h2l[kb][e] = (_Float16)(v - (float)h);
        }
    f32x4 acc3 = b3q;                                      // layer3 (+b3 C-init)
    #pragma unroll
    for (int kb = 0; kb < 4; ++kb) {                       // 12 MFMAs
        f16x8 ah = *(const f16x8*)(bWH3 + kb * 64);
        f16x8 al = *(const f16x8*)(bWL3 + kb * 64);
        acc3 = __builtin_amdgcn_mfma_f32_16x16x32_f16(ah, h2h[kb], acc3, 0, 0, 0);
        acc3 = __builtin_amdgcn_mfma_f32_16x16x32_f16(ah, h2l[kb], acc3, 0, 0, 0);
        acc3 = __builtin_amdgcn_mfma_f32_16x16x32_f16(al, h2h[kb], acc3, 0, 0, 0);
    }
    #pragma unroll
    for (int o = 0; o < 4; ++o) xout[o] = acc3[o];         // valid on ALL lanes
}

__global__ __launch_bounds__(512) void k_dc(const float* __restrict__ Fin,
    const float* __restrict__ w1, const float* __restrict__ b1,
    const float* __restrict__ w2, const float* __restrict__ b2,
    const float* __restrict__ w3, const float* __restrict__ b3,
    float* __restrict__ out, int nelem) {
    extern __shared__ unsigned char s[];
    stage_weights(s, w1, 7, b1, w2, b2, w3, b3);
    __syncthreads();
    const int lane = threadIdx.x & 63;
    const int m = lane & 15, g = lane >> 4;
    const f32x4 b3q = *(const f32x4*)(s + OFF_B3);
    const int wid = blockIdx.x * (blockDim.x >> 6) + (threadIdx.x >> 6);
    const int nw = gridDim.x * (blockDim.x >> 6);
    const int niter = nelem >> 4;
    for (int it = wid; it < niter; it += nw) {
        const int elem = it * 16 + m;
        f32x4 f = ((const f32x4*)Fin)[elem];
        float a = f[0], b = f[1], c = f[2], d = f[3];
        float det = kdet(a, b, c, d);
        float R00, R01, R10, R11;
        polar2(a, b, c, d, det, R00, R01, R10, R11);
        float E = 0.5f * (a + d), Hh = 0.5f * (c - b);
        float Fv = 0.5f * (a - d), G = 0.5f * (b + c);
        float Q = sqrtf(E * E + Hh * Hh), Rr = sqrtf(Fv * Fv + G * G);
        float inv[8];
        inv[0] = Q + Rr - 1.f;
        inv[1] = fabsf(Q - Rr) - 1.f;
        inv[2] = fmaf(a, a, c * c) - 1.f;
        inv[3] = fmaf(a, b, c * d);
        inv[4] = inv[3];
        inv[5] = fmaf(b, b, d * d) - 1.f;
        inv[6] = det - 1.f;
        inv[7] = 1.f;                           // bias column
        f16x8 b1f = build_b1(inv, g);
        float x[4];
        mlp128(s, b1f, m, g, b3q, x);
        float x01 = 0.5f * (x[1] + x[2]);
        float Fp00 = fmaf(R00, x[0], fmaf(R01, x01, a));
        float Fp01 = fmaf(R00, x01, fmaf(R01, x[3], b));
        float Fp10 = fmaf(R10, x[0], fmaf(R11, x01, c));
        float Fp11 = fmaf(R10, x01, fmaf(R11, x[3], d));
        if (g == 0) {
            f32x4 r = {Fp00, Fp01, Fp10, Fp11};
            ((f32x4*)out)[elem] = r;
        }
    }
}

__global__ __launch_bounds__(512) void k_sp(float* io,
    const float* __restrict__ w1, const float* __restrict__ b1,
    const float* __restrict__ w2, const float* __restrict__ b2,
    const float* __restrict__ w3, const float* __restrict__ b3, int nelem) {
    extern __shared__ unsigned char s[];
    stage_weights(s, w1, 3, b1, w2, b2, w3, b3);
    __syncthreads();
    const int lane = threadIdx.x & 63;
    const int m = lane & 15, g = lane >> 4;
    const f32x4 b3q = *(const f32x4*)(s + OFF_B3);
    const int wid = blockIdx.x * (blockDim.x >> 6) + (threadIdx.x >> 6);
    const int nw = gridDim.x * (blockDim.x >> 6);
    const int niter = nelem >> 4;
    for (int it = wid; it < niter; it += nw) {
        const int elem = it * 16 + m;
        f32x4 fp = ((const f32x4*)io)[elem];
        float a = fp[0], b = fp[1], c = fp[2], d = fp[3];
        float det = kdet(a, b, c, d);
        float R00, R01, R10, R11;
        polar2(a, b, c, d, det, R00, R01, R10, R11);
        float E = 0.5f * (a + d), Hh = 0.5f * (c - b);
        float Fv = 0.5f * (a - d), G = 0.5f * (b + c);
        float Q = sqrtf(E * E + Hh * Hh), Rr = sqrtf(Fv * Fv + G * G);
        float inv[8];
        inv[0] = (Q + Rr) + fabsf(Q - Rr) - 2.f;
        inv[1] = fmaf(a, a, fmaf(b, b, fmaf(c, c, d * d))) - 1.f;
        inv[2] = det - 1.f;
        inv[3] = 1.f;                           // bias column
        inv[4] = 0.f; inv[5] = 0.f; inv[6] = 0.f; inv[7] = 0.f;
        f16x8 b1f = build_b1(inv, g);
        float y[4];
        mlp128(s, b1f, m, g, b3q, y);
        float y01 = 0.5f * (y[1] + y[2]);
        float P00 = fmaf(R00, y[0], R01 * y01);
        float P01 = fmaf(R00, y01, R01 * y[3]);
        float P10 = fmaf(R10, y[0], R11 * y01);
        float P11 = fmaf(R10, y01, R11 * y[3]);
        float C00 = fmaf(P00, a, P01 * b);
        float C01 = fmaf(P00, c, P01 * d);
        float C10 = fmaf(P10, a, P11 * b);
        float C11 = fmaf(P10, c, P11 * d);
        if (g == 0) {
            f32x4 r = {C00, C01, C10, C11};
            ((f32x4*)io)[elem] = r;
        }
    }
}

extern "C" void kernel_launch(void* const* d_in, const int* in_sizes, int n_in,
                              void* d_out, int out_size, void* d_ws, size_t ws_size,
                              hipStream_t stream) {
    const float* F     = (const float*)d_in[0];
    const float* dc_w1 = (const float*)d_in[1];
    const float* dc_b1 = (const float*)d_in[2];
    const float* dc_w2 = (const float*)d_in[3];
    const float* dc_b2 = (const float*)d_in[4];
    const float* dc_w3 = (const float*)d_in[5];
    const float* dc_b3 = (const float*)d_in[6];
    const float* sp_w1 = (const float*)d_in[7];
    const float* sp_b1 = (const float*)d_in[8];
    const float* sp_w2 = (const float*)d_in[9];
    const float* sp_b2 = (const float*)d_in[10];
    const float* sp_w3 = (const float*)d_in[11];
    const float* sp_b3 = (const float*)d_in[12];
    float* out = (float*)d_out;
    const int nelem = in_sizes[0] / 4;
    // >64KB dynamic LDS opt-in (host-side attr; graph-capture-safe; idempotent)
    hipFuncSetAttribute((const void*)k_dc,
                        hipFuncAttributeMaxDynamicSharedMemorySize, LDS_BYTES);
    hipFuncSetAttribute((const void*)k_sp,
                        hipFuncAttributeMaxDynamicSharedMemorySize, LDS_BYTES);
    dim3 grid(512), block(512);                 // 2 blocks/CU (80528 B LDS)
    k_dc<<<grid, block, LDS_BYTES, stream>>>(F, dc_w1, dc_b1, dc_w2, dc_b2,
                                             dc_w3, dc_b3, out, nelem);
    k_sp<<<grid, block, LDS_BYTES, stream>>>(out, sp_w1, sp_b1, sp_w2, sp_b2,
                                             sp_w3, sp_b3, nelem);
}

// Round 6
// 446.228 us; speedup vs baseline: 2.0836x; 1.1768x over previous
//
#include <hip/hip_runtime.h>

typedef float f32x4 __attribute__((ext_vector_type(4)));
typedef _Float16 f16x8 __attribute__((ext_vector_type(8)));

#define OFF_W2H 0        /* 128 rows x 256B fp16 hi, XOR-swizzled        */
#define OFF_W2L 32768    /* 128 rows x 256B fp16 lo                      */
#define OFF_W1  65536    /* 128 rows x 64B packed hi/lo K-slots          */
#define OFF_W3H 73728    /* 5 rows x 256B hi (row 4 = shared zero row)   */
#define OFF_W3L 75008    /* 5 rows x 256B lo                             */
#define OFF_B1  76288    /* f32[128] */
#define OFF_B2  76800    /* f32[128] */
#define OFF_B3  77312    /* f32[4]   */
#define LDS_BYTES 77328

#define MFMA16(A, B, C) __builtin_amdgcn_mfma_f32_16x16x32_f16(A, B, C, 0, 0, 0)

// Kahan-accurate 2x2 determinant (sign must match the f64 numpy reference's
// rotation-vs-reflection branch).
__device__ inline float kdet(float a, float b, float c, float d) {
    float w = b * c;
    float e = fmaf(b, c, -w);
    return fmaf(a, d, -w) - e;
}

// Orthogonal polar factor R of F=[[a,b],[c,d]] (== U@Vh of the SVD).
__device__ inline void polar2(float a, float b, float c, float d, float det,
                              float& R00, float& R01, float& R10, float& R11) {
    if (det >= 0.f) {
        float h1 = a + d, h2 = c - b;
        float q = fmaxf(sqrtf(h1 * h1 + h2 * h2), 1e-30f);
        float iq = 1.f / q;
        R00 = h1 * iq; R01 = -h2 * iq; R10 = h2 * iq; R11 = h1 * iq;
    } else {
        float h1 = a - d, h2 = b + c;
        float q = fmaxf(sqrtf(h1 * h1 + h2 * h2), 1e-30f);
        float iq = 1.f / q;
        R00 = h1 * iq; R01 = h2 * iq; R10 = h2 * iq; R11 = -h1 * iq;
    }
}

// Logical K-slot map (A and B sides identical -> permutation cancels):
// k(g,e) = 4g + (e&3) + 16*(e>>2).  Hidden-channel map (C/D absorb):
// c(g,e,kb) = 32kb + 16*(e>>2) + 4g + (e&3).
__device__ inline void stage_weights(unsigned char* s, const float* w1, int D,
                                     const float* b1, const float* w2, const float* b2,
                                     const float* w3, const float* b3) {
    const int tid = threadIdx.x, nt = blockDim.x;
    for (int idx = tid; idx < 2048; idx += nt) {           // w2 hi+lo: (j,kb,g)
        int j = idx >> 4, kb = (idx >> 2) & 3, g = idx & 3;
        const float* src = w2 + j * 128 + kb * 32 + g * 4;
        f16x8 vh, vl;
        #pragma unroll
        for (int e = 0; e < 8; ++e) {
            float w = src[(e & 3) + 16 * (e >> 2)];
            _Float16 h = (_Float16)w;
            vh[e] = h;
            vl[e] = (_Float16)(w - (float)h);
        }
        int off = j * 256 + ((kb * 64 + g * 16) ^ ((j & 7) << 4));
        *(f16x8*)(s + OFF_W2H + off) = vh;
        *(f16x8*)(s + OFF_W2L + off) = vl;
    }
    // w1 packed split: logical k in [0,D): Wh (pairs xh); [8,8+D): Wh (pairs
    // xl); [16,16+D): Wl (pairs xh). One MFMA does all 3 terms.
    for (int idx = tid; idx < 512; idx += nt) {            // (j,g)
        int j = idx >> 2, g = idx & 3;
        f16x8 v;
        #pragma unroll
        for (int e = 0; e < 8; ++e) {
            int k = 4 * g + (e & 3) + 16 * (e >> 2);
            _Float16 val = (_Float16)0.f;
            if (k < D) val = (_Float16)w1[j * D + k];
            else if (k >= 8 && k < 8 + D) val = (_Float16)w1[j * D + (k - 8)];
            else if (k >= 16 && k < 16 + D) {
                float w = w1[j * D + (k - 16)];
                val = (_Float16)(w - (float)(_Float16)w);
            }
            v[e] = val;
        }
        int gg = g ^ ((j ^ (j >> 2)) & 3);
        *(f16x8*)(s + OFF_W1 + j * 64 + gg * 16) = v;
    }
    // w3: 4 real rows + 1 shared zero row (MFMA rows 4..15 alias row 4).
    for (int idx = tid; idx < 80; idx += nt) {             // (j,kb,g), j in 0..4
        int j = idx >> 4, kb = (idx >> 2) & 3, g = idx & 3;
        f16x8 vh, vl;
        #pragma unroll
        for (int e = 0; e < 8; ++e) {
            int c = 32 * kb + 4 * g + (e & 3) + 16 * (e >> 2);
            float w = (j < 4) ? w3[j * 128 + c] : 0.f;
            _Float16 h = (_Float16)w;
            vh[e] = h;
            vl[e] = (_Float16)(w - (float)h);
        }
        int off = j * 256 + ((kb * 64 + g * 16) ^ ((j & 7) << 4));
        *(f16x8*)(s + OFF_W3H + off) = vh;
        *(f16x8*)(s + OFF_W3L + off) = vl;
    }
    for (int idx = tid; idx < 128; idx += nt) {
        ((float*)(s + OFF_B1))[idx] = b1[idx];
        ((float*)(s + OFF_B2))[idx] = b2[idx];
    }
    if (tid < 4) ((float*)(s + OFF_B3))[tid] = b3[tid];
}

// Layer-1 B fragment.  g0:{h0..3,h0..3} g1:{h4..7,h4..7}
// g2:{l0..3,0} g3:{l4..7,0}.
__device__ inline f16x8 build_b1(const float in[8], int g) {
    const bool half2 = (g & 1);
    float t0 = half2 ? in[4] : in[0];
    float t1 = half2 ? in[5] : in[1];
    float t2 = half2 ? in[6] : in[2];
    float t3 = half2 ? in[7] : in[3];
    _Float16 h0 = (_Float16)t0, h1 = (_Float16)t1;
    _Float16 h2 = (_Float16)t2, h3 = (_Float16)t3;
    _Float16 l0 = (_Float16)(t0 - (float)h0), l1 = (_Float16)(t1 - (float)h1);
    _Float16 l2 = (_Float16)(t2 - (float)h2), l3 = (_Float16)(t3 - (float)h3);
    const bool hi = (g < 2);
    const _Float16 z = (_Float16)0.f;
    f16x8 b;
    b[0] = hi ? h0 : l0; b[1] = hi ? h1 : l1;
    b[2] = hi ? h2 : l2; b[3] = hi ? h3 : l3;
    b[4] = hi ? h0 : z;  b[5] = hi ? h1 : z;
    b[6] = hi ? h2 : z;  b[7] = hi ? h3 : z;
    return b;
}

// Split-fp16 3-term MLP (f32 quality), TWO element-sets per wave: every
// A-fragment ds_read feeds 2 MFMAs (halves LDS bytes per element).
__device__ inline void mlp128x2(const unsigned char* s, f16x8 b1fA, f16x8 b1fB,
                                int m, int g, float xA[4], float xB[4]) {
    const f32x4 zero = {0.f, 0.f, 0.f, 0.f};
    f32x4 accA[8], accB[8];
    #pragma unroll
    for (int mb = 0; mb < 8; ++mb) {                       // layer1: 16 MFMAs
        int row = m + 16 * mb;
        int gg = g ^ ((row ^ (row >> 2)) & 3);
        f16x8 af = *(const f16x8*)(s + OFF_W1 + row * 64 + gg * 16);
        accA[mb] = MFMA16(af, b1fA, zero);
        accB[mb] = MFMA16(af, b1fB, zero);
    }
    #pragma unroll
    for (int mb = 0; mb < 8; ++mb) {                       // +b1, relu
        f32x4 bq = *(const f32x4*)(s + OFF_B1 + (mb * 16 + g * 4) * 4);
        #pragma unroll
        for (int r = 0; r < 4; ++r) {
            accA[mb][r] = fmaxf(accA[mb][r] + bq[r], 0.f);
            accB[mb][r] = fmaxf(accB[mb][r] + bq[r], 0.f);
        }
    }
    f16x8 hhA[4], hlA[4], hhB[4], hlB[4];
    #pragma unroll
    for (int kb = 0; kb < 4; ++kb)                         // split repack x2
        #pragma unroll
        for (int e = 0; e < 8; ++e) {
            float vA = accA[2 * kb + (e >> 2)][e & 3];
            _Float16 hA = (_Float16)vA;
            hhA[kb][e] = hA;
            hlA[kb][e] = (_Float16)(vA - (float)hA);
            float vB = accB[2 * kb + (e >> 2)][e & 3];
            _Float16 hB = (_Float16)vB;
            hhB[kb][e] = hB;
            hlB[kb][e] = (_Float16)(vB - (float)hB);
        }
    f32x4 acc2A[8], acc2B[8];
    #pragma unroll
    for (int mb = 0; mb < 8; ++mb) { acc2A[mb] = zero; acc2B[mb] = zero; }
    #pragma unroll
    for (int mb = 0; mb < 8; ++mb) {                       // layer2: 192 MFMAs
        int row = m + 16 * mb;
        #pragma unroll
        for (int kb = 0; kb < 4; ++kb) {
            int off = row * 256 + ((kb * 64 + g * 16) ^ ((row & 7) << 4));
            f16x8 ah = *(const f16x8*)(s + OFF_W2H + off);
            f16x8 al = *(const f16x8*)(s + OFF_W2L + off);
            acc2A[mb] = MFMA16(ah, hhA[kb], acc2A[mb]);
            acc2A[mb] = MFMA16(ah, hlA[kb], acc2A[mb]);
            acc2A[mb] = MFMA16(al, hhA[kb], acc2A[mb]);
            acc2B[mb] = MFMA16(ah, hhB[kb], acc2B[mb]);
            acc2B[mb] = MFMA16(ah, hlB[kb], acc2B[mb]);
            acc2B[mb] = MFMA16(al, hhB[kb], acc2B[mb]);
        }
    }
    #pragma unroll
    for (int mb = 0; mb < 8; ++mb) {                       // +b2, relu
        f32x4 bq = *(const f32x4*)(s + OFF_B2 + (mb * 16 + g * 4) * 4);
        #pragma unroll
        for (int r = 0; r < 4; ++r) {
            acc2A[mb][r] = fmaxf(acc2A[mb][r] + bq[r], 0.f);
            acc2B[mb][r] = fmaxf(acc2B[mb][r] + bq[r], 0.f);
        }
    }
    f16x8 h2hA[4], h2lA[4], h2hB[4], h2lB[4];
    #pragma unroll
    for (int kb = 0; kb < 4; ++kb)                         // split repack x2
        #pragma unroll
        for (int e = 0; e < 8; ++e) {
            float vA = acc2A[2 * kb + (e >> 2)][e & 3];
            _Float16 hA = (_Float16)vA;
            h2hA[kb][e] = hA;
            h2lA[kb][e] = (_Float16)(vA - (float)hA);
            float vB = acc2B[2 * kb + (e >> 2)][e & 3];
            _Float16 hB = (_Float16)vB;
            h2hB[kb][e] = hB;
            h2lB[kb][e] = (_Float16)(vB - (float)hB);
        }
    f32x4 acc3A = zero, acc3B = zero;
    const int r3 = (m < 4) ? m : 4;                        // rows>=4 alias zero
    #pragma unroll
    for (int kb = 0; kb < 4; ++kb) {                       // layer3: 24 MFMAs
        int off = r3 * 256 + ((kb * 64 + g * 16) ^ ((r3 & 7) << 4));
        f16x8 ah = *(const f16x8*)(s + OFF_W3H + off);
        f16x8 al = *(const f16x8*)(s + OFF_W3L + off);
        acc3A = MFMA16(ah, h2hA[kb], acc3A);
        acc3A = MFMA16(ah, h2lA[kb], acc3A);
        acc3A = MFMA16(al, h2hA[kb], acc3A);
        acc3B = MFMA16(ah, h2hB[kb], acc3B);
        acc3B = MFMA16(ah, h2lB[kb], acc3B);
        acc3B = MFMA16(al, h2hB[kb], acc3B);
    }
    f32x4 b3q = *(const f32x4*)(s + OFF_B3);
    #pragma unroll
    for (int o = 0; o < 4; ++o) {                          // broadcast from g==0
        xA[o] = __shfl(acc3A[o] + b3q[o], m, 64);
        xB[o] = __shfl(acc3B[o] + b3q[o], m, 64);
    }
}

__device__ inline f16x8 dc_pre(const f32x4 f, int g, float& R00, float& R01,
                               float& R10, float& R11) {
    float a = f[0], b = f[1], c = f[2], d = f[3];
    float det = kdet(a, b, c, d);
    polar2(a, b, c, d, det, R00, R01, R10, R11);
    float E = 0.5f * (a + d), Hh = 0.5f * (c - b);
    float Fv = 0.5f * (a - d), G = 0.5f * (b + c);
    float Q = sqrtf(E * E + Hh * Hh), Rr = sqrtf(Fv * Fv + G * G);
    float inv[8];
    inv[0] = Q + Rr - 1.f;
    inv[1] = fabsf(Q - Rr) - 1.f;
    inv[2] = fmaf(a, a, c * c) - 1.f;
    inv[3] = fmaf(a, b, c * d);
    inv[4] = inv[3];
    inv[5] = fmaf(b, b, d * d) - 1.f;
    inv[6] = det - 1.f;
    inv[7] = 0.f;
    return build_b1(inv, g);
}

__device__ inline f16x8 sp_pre(const f32x4 fp, int g, float& R00, float& R01,
                               float& R10, float& R11) {
    float a = fp[0], b = fp[1], c = fp[2], d = fp[3];
    float det = kdet(a, b, c, d);
    polar2(a, b, c, d, det, R00, R01, R10, R11);
    float E = 0.5f * (a + d), Hh = 0.5f * (c - b);
    float Fv = 0.5f * (a - d), G = 0.5f * (b + c);
    float Q = sqrtf(E * E + Hh * Hh), Rr = sqrtf(Fv * Fv + G * G);
    float inv[8];
    inv[0] = (Q + Rr) + fabsf(Q - Rr) - 2.f;
    inv[1] = fmaf(a, a, fmaf(b, b, fmaf(c, c, d * d))) - 1.f;
    inv[2] = det - 1.f;
    inv[3] = 0.f; inv[4] = 0.f; inv[5] = 0.f; inv[6] = 0.f; inv[7] = 0.f;
    return build_b1(inv, g);
}

__device__ inline f32x4 dc_post(const float x[4], const f32x4 f,
                                float R00, float R01, float R10, float R11) {
    float x01 = 0.5f * (x[1] + x[2]);
    f32x4 r;
    r[0] = fmaf(R00, x[0], fmaf(R01, x01, f[0]));
    r[1] = fmaf(R00, x01, fmaf(R01, x[3], f[1]));
    r[2] = fmaf(R10, x[0], fmaf(R11, x01, f[2]));
    r[3] = fmaf(R10, x01, fmaf(R11, x[3], f[3]));
    return r;
}

__device__ inline f32x4 sp_post(const float y[4], const f32x4 fp,
                                float R00, float R01, float R10, float R11) {
    float y01 = 0.5f * (y[1] + y[2]);
    float P00 = fmaf(R00, y[0], R01 * y01);
    float P01 = fmaf(R00, y01, R01 * y[3]);
    float P10 = fmaf(R10, y[0], R11 * y01);
    float P11 = fmaf(R10, y01, R11 * y[3]);
    f32x4 r;                                   // cauchy = P @ Fp^T
    r[0] = fmaf(P00, fp[0], P01 * fp[1]);
    r[1] = fmaf(P00, fp[2], P01 * fp[3]);
    r[2] = fmaf(P10, fp[0], P11 * fp[1]);
    r[3] = fmaf(P10, fp[2], P11 * fp[3]);
    return r;
}

__global__ __launch_bounds__(256, 2) void k_dc(const float* __restrict__ Fin,
    const float* __restrict__ w1, const float* __restrict__ b1,
    const float* __restrict__ w2, const float* __restrict__ b2,
    const float* __restrict__ w3, const float* __restrict__ b3,
    float* __restrict__ out, int nelem) {
    extern __shared__ unsigned char s[];
    stage_weights(s, w1, 7, b1, w2, b2, w3, b3);
    __syncthreads();
    const int lane = threadIdx.x & 63;
    const int m = lane & 15, g = lane >> 4;
    const int wid = blockIdx.x * (blockDim.x >> 6) + (threadIdx.x >> 6);
    const int nw = gridDim.x * (blockDim.x >> 6);
    const int niter = nelem >> 5;
    for (int it = wid; it < niter; it += nw) {
        const int eA = it * 32 + m, eB = eA + 16;
        f32x4 fA = ((const f32x4*)Fin)[eA];
        f32x4 fB = ((const f32x4*)Fin)[eB];
        float RA00, RA01, RA10, RA11, RB00, RB01, RB10, RB11;
        f16x8 b1fA = dc_pre(fA, g, RA00, RA01, RA10, RA11);
        f16x8 b1fB = dc_pre(fB, g, RB00, RB01, RB10, RB11);
        float xA[4], xB[4];
        mlp128x2(s, b1fA, b1fB, m, g, xA, xB);
        f32x4 rA = dc_post(xA, fA, RA00, RA01, RA10, RA11);
        f32x4 rB = dc_post(xB, fB, RB00, RB01, RB10, RB11);
        if (g == 0) {
            ((f32x4*)out)[eA] = rA;            // stage Fp in d_out
            ((f32x4*)out)[eB] = rB;
        }
    }
}

__global__ __launch_bounds__(256, 2) void k_sp(float* io,
    const float* __restrict__ w1, const float* __restrict__ b1,
    const float* __restrict__ w2, const float* __restrict__ b2,
    const float* __restrict__ w3, const float* __restrict__ b3, int nelem) {
    extern __shared__ unsigned char s[];
    stage_weights(s, w1, 3, b1, w2, b2, w3, b3);
    __syncthreads();
    const int lane = threadIdx.x & 63;
    const int m = lane & 15, g = lane >> 4;
    const int wid = blockIdx.x * (blockDim.x >> 6) + (threadIdx.x >> 6);
    const int nw = gridDim.x * (blockDim.x >> 6);
    const int niter = nelem >> 5;
    for (int it = wid; it < niter; it += nw) {
        const int eA = it * 32 + m, eB = eA + 16;
        f32x4 fA = ((const f32x4*)io)[eA];     // Fp from k_dc
        f32x4 fB = ((const f32x4*)io)[eB];
        float RA00, RA01, RA10, RA11, RB00, RB01, RB10, RB11;
        f16x8 b1fA = sp_pre(fA, g, RA00, RA01, RA10, RA11);
        f16x8 b1fB = sp_pre(fB, g, RB00, RB01, RB10, RB11);
        float yA[4], yB[4];
        mlp128x2(s, b1fA, b1fB, m, g, yA, yB);
        f32x4 rA = sp_post(yA, fA, RA00, RA01, RA10, RA11);
        f32x4 rB = sp_post(yB, fB, RB00, RB01, RB10, RB11);
        if (g == 0) {
            ((f32x4*)io)[eA] = rA;
            ((f32x4*)io)[eB] = rB;
        }
    }
}

extern "C" void kernel_launch(void* const* d_in, const int* in_sizes, int n_in,
                              void* d_out, int out_size, void* d_ws, size_t ws_size,
                              hipStream_t stream) {
    const float* F     = (const float*)d_in[0];
    const float* dc_w1 = (const float*)d_in[1];
    const float* dc_b1 = (const float*)d_in[2];
    const float* dc_w2 = (const float*)d_in[3];
    const float* dc_b2 = (const float*)d_in[4];
    const float* dc_w3 = (const float*)d_in[5];
    const float* dc_b3 = (const float*)d_in[6];
    const float* sp_w1 = (const float*)d_in[7];
    const float* sp_b1 = (const float*)d_in[8];
    const float* sp_w2 = (const float*)d_in[9];
    const float* sp_b2 = (const float*)d_in[10];
    const float* sp_w3 = (const float*)d_in[11];
    const float* sp_b3 = (const float*)d_in[12];
    float* out = (float*)d_out;
    const int nelem = in_sizes[0] / 4;
    // >64KB dynamic LDS opt-in (host-side attr; graph-capture-safe; idempotent)
    hipFuncSetAttribute((const void*)k_dc,
                        hipFuncAttributeMaxDynamicSharedMemorySize, LDS_BYTES);
    hipFuncSetAttribute((const void*)k_sp,
                        hipFuncAttributeMaxDynamicSharedMemorySize, LDS_BYTES);
    dim3 grid(512), block(256);  // 2 blocks/CU, 8 waves/CU, VGPR cap 256
    k_dc<<<grid, block, LDS_BYTES, stream>>>(F, dc_w1, dc_b1, dc_w2, dc_b2,
                                             dc_w3, dc_b3, out, nelem);
    k_sp<<<grid, block, LDS_BYTES, stream>>>(out, sp_w1, sp_b1, sp_w2, sp_b2,
                                             sp_w3, sp_b3, nelem);
}

// Round 7
// 175.005 us; speedup vs baseline: 5.3127x; 2.5498x over previous
//
#include <hip/hip_runtime.h>

typedef float f32x4 __attribute__((ext_vector_type(4)));
typedef _Float16 f16x8 __attribute__((ext_vector_type(8)));

#define OFF_W2H 0        /* 128 rows x 256B fp16 hi, XOR-swizzled        */
#define OFF_W2L 32768    /* 128 rows x 256B fp16 lo                      */
#define OFF_W1  65536    /* 128 rows x 64B packed hi/lo K-slots          */
#define OFF_W3H 73728    /* 5 rows x 256B hi (row 4 = shared zero row)   */
#define OFF_W3L 75008    /* 5 rows x 256B lo                             */
#define OFF_B1  76288    /* f32[128] */
#define OFF_B2  76800    /* f32[128] */
#define OFF_B3  77312    /* f32[4]   */
#define LDS_BYTES 77328

#define MFMA16(A, B, C) __builtin_amdgcn_mfma_f32_16x16x32_f16(A, B, C, 0, 0, 0)

// Kahan-accurate 2x2 determinant (sign must match the f64 numpy reference's
// rotation-vs-reflection branch).
__device__ inline float kdet(float a, float b, float c, float d) {
    float w = b * c;
    float e = fmaf(b, c, -w);
    return fmaf(a, d, -w) - e;
}

// Orthogonal polar factor R of F=[[a,b],[c,d]] (== U@Vh of the SVD).
__device__ inline void polar2(float a, float b, float c, float d, float det,
                              float& R00, float& R01, float& R10, float& R11) {
    if (det >= 0.f) {
        float h1 = a + d, h2 = c - b;
        float q = fmaxf(sqrtf(h1 * h1 + h2 * h2), 1e-30f);
        float iq = 1.f / q;
        R00 = h1 * iq; R01 = -h2 * iq; R10 = h2 * iq; R11 = h1 * iq;
    } else {
        float h1 = a - d, h2 = b + c;
        float q = fmaxf(sqrtf(h1 * h1 + h2 * h2), 1e-30f);
        float iq = 1.f / q;
        R00 = h1 * iq; R01 = h2 * iq; R10 = h2 * iq; R11 = -h1 * iq;
    }
}

// Logical K-slot map (A and B sides identical -> permutation cancels):
// k(g,e) = 4g + (e&3) + 16*(e>>2).  Hidden-channel map (C/D absorb):
// c(g,e,kb) = 32kb + 16*(e>>2) + 4g + (e&3).
__device__ inline void stage_weights(unsigned char* s, const float* w1, int D,
                                     const float* b1, const float* w2, const float* b2,
                                     const float* w3, const float* b3) {
    const int tid = threadIdx.x, nt = blockDim.x;
    for (int idx = tid; idx < 2048; idx += nt) {           // w2 hi+lo: (j,kb,g)
        int j = idx >> 4, kb = (idx >> 2) & 3, g = idx & 3;
        const float* src = w2 + j * 128 + kb * 32 + g * 4;
        f16x8 vh, vl;
        #pragma unroll
        for (int e = 0; e < 8; ++e) {
            float w = src[(e & 3) + 16 * (e >> 2)];
            _Float16 h = (_Float16)w;
            vh[e] = h;
            vl[e] = (_Float16)(w - (float)h);
        }
        int off = j * 256 + ((kb * 64 + g * 16) ^ ((j & 7) << 4));
        *(f16x8*)(s + OFF_W2H + off) = vh;
        *(f16x8*)(s + OFF_W2L + off) = vl;
    }
    // w1 packed split: logical k in [0,D): Wh (pairs xh); [8,8+D): Wh (pairs
    // xl); [16,16+D): Wl (pairs xh). One MFMA does all 3 terms.
    for (int idx = tid; idx < 512; idx += nt) {            // (j,g)
        int j = idx >> 2, g = idx & 3;
        f16x8 v;
        #pragma unroll
        for (int e = 0; e < 8; ++e) {
            int k = 4 * g + (e & 3) + 16 * (e >> 2);
            _Float16 val = (_Float16)0.f;
            if (k < D) val = (_Float16)w1[j * D + k];
            else if (k >= 8 && k < 8 + D) val = (_Float16)w1[j * D + (k - 8)];
            else if (k >= 16 && k < 16 + D) {
                float w = w1[j * D + (k - 16)];
                val = (_Float16)(w - (float)(_Float16)w);
            }
            v[e] = val;
        }
        int gg = g ^ ((j ^ (j >> 2)) & 3);
        *(f16x8*)(s + OFF_W1 + j * 64 + gg * 16) = v;
    }
    // w3: 4 real rows + 1 shared zero row (MFMA rows 4..15 alias row 4).
    for (int idx = tid; idx < 80; idx += nt) {             // (j,kb,g), j in 0..4
        int j = idx >> 4, kb = (idx >> 2) & 3, g = idx & 3;
        f16x8 vh, vl;
        #pragma unroll
        for (int e = 0; e < 8; ++e) {
            int c = 32 * kb + 4 * g + (e & 3) + 16 * (e >> 2);
            float w = (j < 4) ? w3[j * 128 + c] : 0.f;
            _Float16 h = (_Float16)w;
            vh[e] = h;
            vl[e] = (_Float16)(w - (float)h);
        }
        int off = j * 256 + ((kb * 64 + g * 16) ^ ((j & 7) << 4));
        *(f16x8*)(s + OFF_W3H + off) = vh;
        *(f16x8*)(s + OFF_W3L + off) = vl;
    }
    for (int idx = tid; idx < 128; idx += nt) {
        ((float*)(s + OFF_B1))[idx] = b1[idx];
        ((float*)(s + OFF_B2))[idx] = b2[idx];
    }
    if (tid < 4) ((float*)(s + OFF_B3))[tid] = b3[tid];
}

// Layer-1 B fragment.  g0:{h0..3,h0..3} g1:{h4..7,h4..7}
// g2:{l0..3,0} g3:{l4..7,0}.
__device__ inline f16x8 build_b1(const float in[8], int g) {
    const bool half2 = (g & 1);
    float t0 = half2 ? in[4] : in[0];
    float t1 = half2 ? in[5] : in[1];
    float t2 = half2 ? in[6] : in[2];
    float t3 = half2 ? in[7] : in[3];
    _Float16 h0 = (_Float16)t0, h1 = (_Float16)t1;
    _Float16 h2 = (_Float16)t2, h3 = (_Float16)t3;
    _Float16 l0 = (_Float16)(t0 - (float)h0), l1 = (_Float16)(t1 - (float)h1);
    _Float16 l2 = (_Float16)(t2 - (float)h2), l3 = (_Float16)(t3 - (float)h3);
    const bool hi = (g < 2);
    const _Float16 z = (_Float16)0.f;
    f16x8 b;
    b[0] = hi ? h0 : l0; b[1] = hi ? h1 : l1;
    b[2] = hi ? h2 : l2; b[3] = hi ? h3 : l3;
    b[4] = hi ? h0 : z;  b[5] = hi ? h1 : z;
    b[6] = hi ? h2 : z;  b[7] = hi ? h3 : z;
    return b;
}

// Split-fp16 3-term MLP (f32 quality), TWO element-sets per wave: every
// A-fragment ds_read feeds 2 MFMAs (halves LDS bytes per element).
__device__ inline void mlp128x2(const unsigned char* s, f16x8 b1fA, f16x8 b1fB,
                                int m, int g, float xA[4], float xB[4]) {
    const f32x4 zero = {0.f, 0.f, 0.f, 0.f};
    f32x4 accA[8], accB[8];
    #pragma unroll
    for (int mb = 0; mb < 8; ++mb) {                       // layer1: 16 MFMAs
        int row = m + 16 * mb;
        int gg = g ^ ((row ^ (row >> 2)) & 3);
        f16x8 af = *(const f16x8*)(s + OFF_W1 + row * 64 + gg * 16);
        accA[mb] = MFMA16(af, b1fA, zero);
        accB[mb] = MFMA16(af, b1fB, zero);
    }
    #pragma unroll
    for (int mb = 0; mb < 8; ++mb) {                       // +b1, relu
        f32x4 bq = *(const f32x4*)(s + OFF_B1 + (mb * 16 + g * 4) * 4);
        #pragma unroll
        for (int r = 0; r < 4; ++r) {
            accA[mb][r] = fmaxf(accA[mb][r] + bq[r], 0.f);
            accB[mb][r] = fmaxf(accB[mb][r] + bq[r], 0.f);
        }
    }
    f16x8 hhA[4], hlA[4], hhB[4], hlB[4];
    #pragma unroll
    for (int kb = 0; kb < 4; ++kb)                         // split repack x2
        #pragma unroll
        for (int e = 0; e < 8; ++e) {
            float vA = accA[2 * kb + (e >> 2)][e & 3];
            _Float16 hA = (_Float16)vA;
            hhA[kb][e] = hA;
            hlA[kb][e] = (_Float16)(vA - (float)hA);
            float vB = accB[2 * kb + (e >> 2)][e & 3];
            _Float16 hB = (_Float16)vB;
            hhB[kb][e] = hB;
            hlB[kb][e] = (_Float16)(vB - (float)hB);
        }
    f32x4 acc2A[8], acc2B[8];
    #pragma unroll
    for (int mb = 0; mb < 8; ++mb) { acc2A[mb] = zero; acc2B[mb] = zero; }
    #pragma unroll
    for (int mb = 0; mb < 8; ++mb) {                       // layer2: 192 MFMAs
        int row = m + 16 * mb;
        #pragma unroll
        for (int kb = 0; kb < 4; ++kb) {
            int off = row * 256 + ((kb * 64 + g * 16) ^ ((row & 7) << 4));
            f16x8 ah = *(const f16x8*)(s + OFF_W2H + off);
            f16x8 al = *(const f16x8*)(s + OFF_W2L + off);
            acc2A[mb] = MFMA16(ah, hhA[kb], acc2A[mb]);
            acc2A[mb] = MFMA16(ah, hlA[kb], acc2A[mb]);
            acc2A[mb] = MFMA16(al, hhA[kb], acc2A[mb]);
            acc2B[mb] = MFMA16(ah, hhB[kb], acc2B[mb]);
            acc2B[mb] = MFMA16(ah, hlB[kb], acc2B[mb]);
            acc2B[mb] = MFMA16(al, hhB[kb], acc2B[mb]);
        }
    }
    #pragma unroll
    for (int mb = 0; mb < 8; ++mb) {                       // +b2, relu
        f32x4 bq = *(const f32x4*)(s + OFF_B2 + (mb * 16 + g * 4) * 4);
        #pragma unroll
        for (int r = 0; r < 4; ++r) {
            acc2A[mb][r] = fmaxf(acc2A[mb][r] + bq[r], 0.f);
            acc2B[mb][r] = fmaxf(acc2B[mb][r] + bq[r], 0.f);
        }
    }
    f16x8 h2hA[4], h2lA[4], h2hB[4], h2lB[4];
    #pragma unroll
    for (int kb = 0; kb < 4; ++kb)                         // split repack x2
        #pragma unroll
        for (int e = 0; e < 8; ++e) {
            float vA = acc2A[2 * kb + (e >> 2)][e & 3];
            _Float16 hA = (_Float16)vA;
            h2hA[kb][e] = hA;
            h2lA[kb][e] = (_Float16)(vA - (float)hA);
            float vB = acc2B[2 * kb + (e >> 2)][e & 3];
            _Float16 hB = (_Float16)vB;
            h2hB[kb][e] = hB;
            h2lB[kb][e] = (_Float16)(vB - (float)hB);
        }
    f32x4 acc3A = zero, acc3B = zero;
    const int r3 = (m < 4) ? m : 4;                        // rows>=4 alias zero
    #pragma unroll
    for (int kb = 0; kb < 4; ++kb) {                       // layer3: 24 MFMAs
        int off = r3 * 256 + ((kb * 64 + g * 16) ^ ((r3 & 7) << 4));
        f16x8 ah = *(const f16x8*)(s + OFF_W3H + off);
        f16x8 al = *(const f16x8*)(s + OFF_W3L + off);
        acc3A = MFMA16(ah, h2hA[kb], acc3A);
        acc3A = MFMA16(ah, h2lA[kb], acc3A);
        acc3A = MFMA16(al, h2hA[kb], acc3A);
        acc3B = MFMA16(ah, h2hB[kb], acc3B);
        acc3B = MFMA16(ah, h2lB[kb], acc3B);
        acc3B = MFMA16(al, h2hB[kb], acc3B);
    }
    f32x4 b3q = *(const f32x4*)(s + OFF_B3);
    #pragma unroll
    for (int o = 0; o < 4; ++o) {                          // broadcast from g==0
        xA[o] = __shfl(acc3A[o] + b3q[o], m, 64);
        xB[o] = __shfl(acc3B[o] + b3q[o], m, 64);
    }
}

__device__ inline f16x8 dc_pre(const f32x4 f, int g, float& R00, float& R01,
                               float& R10, float& R11) {
    float a = f[0], b = f[1], c = f[2], d = f[3];
    float det = kdet(a, b, c, d);
    polar2(a, b, c, d, det, R00, R01, R10, R11);
    float E = 0.5f * (a + d), Hh = 0.5f * (c - b);
    float Fv = 0.5f * (a - d), G = 0.5f * (b + c);
    float Q = sqrtf(E * E + Hh * Hh), Rr = sqrtf(Fv * Fv + G * G);
    float inv[8];
    inv[0] = Q + Rr - 1.f;
    inv[1] = fabsf(Q - Rr) - 1.f;
    inv[2] = fmaf(a, a, c * c) - 1.f;
    inv[3] = fmaf(a, b, c * d);
    inv[4] = inv[3];
    inv[5] = fmaf(b, b, d * d) - 1.f;
    inv[6] = det - 1.f;
    inv[7] = 0.f;
    return build_b1(inv, g);
}

__device__ inline f16x8 sp_pre(const f32x4 fp, int g, float& R00, float& R01,
                               float& R10, float& R11) {
    float a = fp[0], b = fp[1], c = fp[2], d = fp[3];
    float det = kdet(a, b, c, d);
    polar2(a, b, c, d, det, R00, R01, R10, R11);
    float E = 0.5f * (a + d), Hh = 0.5f * (c - b);
    float Fv = 0.5f * (a - d), G = 0.5f * (b + c);
    float Q = sqrtf(E * E + Hh * Hh), Rr = sqrtf(Fv * Fv + G * G);
    float inv[8];
    inv[0] = (Q + Rr) + fabsf(Q - Rr) - 2.f;
    inv[1] = fmaf(a, a, fmaf(b, b, fmaf(c, c, d * d))) - 1.f;
    inv[2] = det - 1.f;
    inv[3] = 0.f; inv[4] = 0.f; inv[5] = 0.f; inv[6] = 0.f; inv[7] = 0.f;
    return build_b1(inv, g);
}

__device__ inline f32x4 dc_post(const float x[4], const f32x4 f,
                                float R00, float R01, float R10, float R11) {
    float x01 = 0.5f * (x[1] + x[2]);
    f32x4 r;
    r[0] = fmaf(R00, x[0], fmaf(R01, x01, f[0]));
    r[1] = fmaf(R00, x01, fmaf(R01, x[3], f[1]));
    r[2] = fmaf(R10, x[0], fmaf(R11, x01, f[2]));
    r[3] = fmaf(R10, x01, fmaf(R11, x[3], f[3]));
    return r;
}

__device__ inline f32x4 sp_post(const float y[4], const f32x4 fp,
                                float R00, float R01, float R10, float R11) {
    float y01 = 0.5f * (y[1] + y[2]);
    float P00 = fmaf(R00, y[0], R01 * y01);
    float P01 = fmaf(R00, y01, R01 * y[3]);
    float P10 = fmaf(R10, y[0], R11 * y01);
    float P11 = fmaf(R10, y01, R11 * y[3]);
    f32x4 r;                                   // cauchy = P @ Fp^T
    r[0] = fmaf(P00, fp[0], P01 * fp[1]);
    r[1] = fmaf(P00, fp[2], P01 * fp[3]);
    r[2] = fmaf(P10, fp[0], P11 * fp[1]);
    r[3] = fmaf(P10, fp[2], P11 * fp[3]);
    return r;
}

__global__ __launch_bounds__(256)
__attribute__((amdgpu_waves_per_eu(1, 2)))   // cap 512 regs: spill impossible
void k_dc(const float* __restrict__ Fin,
    const float* __restrict__ w1, const float* __restrict__ b1,
    const float* __restrict__ w2, const float* __restrict__ b2,
    const float* __restrict__ w3, const float* __restrict__ b3,
    float* __restrict__ out, int nelem) {
    extern __shared__ unsigned char s[];
    stage_weights(s, w1, 7, b1, w2, b2, w3, b3);
    __syncthreads();
    const int lane = threadIdx.x & 63;
    const int m = lane & 15, g = lane >> 4;
    const int wid = blockIdx.x * (blockDim.x >> 6) + (threadIdx.x >> 6);
    const int nw = gridDim.x * (blockDim.x >> 6);
    const int niter = nelem >> 5;
    for (int it = wid; it < niter; it += nw) {
        const int eA = it * 32 + m, eB = eA + 16;
        f32x4 fA = ((const f32x4*)Fin)[eA];
        f32x4 fB = ((const f32x4*)Fin)[eB];
        float RA00, RA01, RA10, RA11, RB00, RB01, RB10, RB11;
        f16x8 b1fA = dc_pre(fA, g, RA00, RA01, RA10, RA11);
        f16x8 b1fB = dc_pre(fB, g, RB00, RB01, RB10, RB11);
        float xA[4], xB[4];
        mlp128x2(s, b1fA, b1fB, m, g, xA, xB);
        f32x4 rA = dc_post(xA, fA, RA00, RA01, RA10, RA11);
        f32x4 rB = dc_post(xB, fB, RB00, RB01, RB10, RB11);
        if (g == 0) {
            ((f32x4*)out)[eA] = rA;            // stage Fp in d_out
            ((f32x4*)out)[eB] = rB;
        }
    }
}

__global__ __launch_bounds__(256)
__attribute__((amdgpu_waves_per_eu(1, 2)))
void k_sp(float* io,
    const float* __restrict__ w1, const float* __restrict__ b1,
    const float* __restrict__ w2, const float* __restrict__ b2,
    const float* __restrict__ w3, const float* __restrict__ b3, int nelem) {
    extern __shared__ unsigned char s[];
    stage_weights(s, w1, 3, b1, w2, b2, w3, b3);
    __syncthreads();
    const int lane = threadIdx.x & 63;
    const int m = lane & 15, g = lane >> 4;
    const int wid = blockIdx.x * (blockDim.x >> 6) + (threadIdx.x >> 6);
    const int nw = gridDim.x * (blockDim.x >> 6);
    const int niter = nelem >> 5;
    for (int it = wid; it < niter; it += nw) {
        const int eA = it * 32 + m, eB = eA + 16;
        f32x4 fA = ((const f32x4*)io)[eA];     // Fp from k_dc
        f32x4 fB = ((const f32x4*)io)[eB];
        float RA00, RA01, RA10, RA11, RB00, RB01, RB10, RB11;
        f16x8 b1fA = sp_pre(fA, g, RA00, RA01, RA10, RA11);
        f16x8 b1fB = sp_pre(fB, g, RB00, RB01, RB10, RB11);
        float yA[4], yB[4];
        mlp128x2(s, b1fA, b1fB, m, g, yA, yB);
        f32x4 rA = sp_post(yA, fA, RA00, RA01, RA10, RA11);
        f32x4 rB = sp_post(yB, fB, RB00, RB01, RB10, RB11);
        if (g == 0) {
            ((f32x4*)io)[eA] = rA;
            ((f32x4*)io)[eB] = rB;
        }
    }
}

extern "C" void kernel_launch(void* const* d_in, const int* in_sizes, int n_in,
                              void* d_out, int out_size, void* d_ws, size_t ws_size,
                              hipStream_t stream) {
    const float* F     = (const float*)d_in[0];
    const float* dc_w1 = (const float*)d_in[1];
    const float* dc_b1 = (const float*)d_in[2];
    const float* dc_w2 = (const float*)d_in[3];
    const float* dc_b2 = (const float*)d_in[4];
    const float* dc_w3 = (const float*)d_in[5];
    const float* dc_b3 = (const float*)d_in[6];
    const float* sp_w1 = (const float*)d_in[7];
    const float* sp_b1 = (const float*)d_in[8];
    const float* sp_w2 = (const float*)d_in[9];
    const float* sp_b2 = (const float*)d_in[10];
    const float* sp_w3 = (const float*)d_in[11];
    const float* sp_b3 = (const float*)d_in[12];
    float* out = (float*)d_out;
    const int nelem = in_sizes[0] / 4;
    // >64KB dynamic LDS opt-in (host-side attr; graph-capture-safe; idempotent)
    hipFuncSetAttribute((const void*)k_dc,
                        hipFuncAttributeMaxDynamicSharedMemorySize, LDS_BYTES);
    hipFuncSetAttribute((const void*)k_sp,
                        hipFuncAttributeMaxDynamicSharedMemorySize, LDS_BYTES);
    dim3 grid(512), block(256);  // 2 blocks/CU (LDS), 8 waves/CU
    k_dc<<<grid, block, LDS_BYTES, stream>>>(F, dc_w1, dc_b1, dc_w2, dc_b2,
                                             dc_w3, dc_b3, out, nelem);
    k_sp<<<grid, block, LDS_BYTES, stream>>>(out, sp_w1, sp_b1, sp_w2, sp_b2,
                                             sp_w3, sp_b3, nelem);
}